// Round 1
// baseline (455.511 us; speedup 1.0000x reference)
//
#include <hip/hip_runtime.h>

// SparseInputLayer: inputs [B, ND*(1+NS)] fp32.
//  - cols [0,64): channel indices (float-encoded ints in [0,384))
//  - cols [64, 64+64*121): data rows x[b][j][s]
// out[b][c][s] = sum_{j: idx[b][j]==c} x[b][j][s], shape [2048,384,121,1] fp32.
//
// Strategy: one block per batch. Build per-channel 64-bit "which j maps here"
// bitmask in LDS, then stream the output row in 16B quads (float4 stores).
// Row base is 16B-aligned (46464 floats * 4B per row), so flat quads are
// aligned. A quad crosses a channel boundary only when (c % 4 != 0) at that
// boundary (~2.5% of quads) -> scalar fallback. ~85% of quads are zero-mask:
// they cost one div + one ds_read_b64 + one dwordx4 store per 16 bytes.

#define BATCH 2048
#define N_DENSE 64
#define N_SAMPLES 121
#define N_CHANNELS 384
#define ROW_IN (N_DENSE * (1 + N_SAMPLES)) // 7808 floats per input row
#define ROW_OUT (N_CHANNELS * N_SAMPLES)   // 46464 floats per output row
#define NQUAD (ROW_OUT / 4)                // 11616 16B quads per row
#define BLOCK 256

__global__ __launch_bounds__(BLOCK) void sparse_scatter_kernel(
    const float* __restrict__ in, float* __restrict__ out) {
  __shared__ unsigned long long mask[N_CHANNELS];

  const int b = blockIdx.x;
  const int tid = threadIdx.x;

  // init per-channel membership masks
  for (int c = tid; c < N_CHANNELS; c += BLOCK) mask[c] = 0ull;
  __syncthreads();

  // threads 0..63 each own one dense slot j; set bit j in its channel's mask
  if (tid < N_DENSE) {
    const int c = (int)in[(size_t)b * ROW_IN + tid];
    atomicOr(&mask[c], 1ull << tid);
  }
  __syncthreads();

  const float* __restrict__ x = in + (size_t)b * ROW_IN + N_DENSE; // [64][121]
  float* __restrict__ o = out + (size_t)b * ROW_OUT;               // [384][121]

  // stream the output row as 16B quads
  for (int q = tid; q < NQUAD; q += BLOCK) {
    const int e = q * 4;
    const int c0 = e / N_SAMPLES;        // magic-mul, no HW div
    const int s0 = e - c0 * N_SAMPLES;
    float4 v = make_float4(0.f, 0.f, 0.f, 0.f);

    if (s0 <= N_SAMPLES - 4) {
      // fast path: all 4 elements in channel c0
      unsigned long long m = mask[c0];   // LDS broadcast within the c-group
      while (m) {
        const int j = __builtin_ctzll(m);
        m &= m - 1;
        const float* __restrict__ xp = x + j * N_SAMPLES + s0;
        v.x += xp[0];
        v.y += xp[1];
        v.z += xp[2];
        v.w += xp[3];
      }
    } else {
      // slow path (~2.5% of quads): quad straddles a channel boundary
      float acc[4] = {0.f, 0.f, 0.f, 0.f};
#pragma unroll
      for (int k = 0; k < 4; ++k) {
        const int ee = e + k;
        const int c = ee / N_SAMPLES;
        const int s = ee - c * N_SAMPLES;
        unsigned long long m = mask[c];
        while (m) {
          const int j = __builtin_ctzll(m);
          m &= m - 1;
          acc[k] += x[j * N_SAMPLES + s];
        }
      }
      v = make_float4(acc[0], acc[1], acc[2], acc[3]);
    }

    *reinterpret_cast<float4*>(o + e) = v; // exactly-once, aligned, coalesced
  }
}

extern "C" void kernel_launch(void* const* d_in, const int* in_sizes, int n_in,
                              void* d_out, int out_size, void* d_ws, size_t ws_size,
                              hipStream_t stream) {
  const float* in = (const float*)d_in[0];
  float* out = (float*)d_out;
  sparse_scatter_kernel<<<BATCH, BLOCK, 0, stream>>>(in, out);
}